// Round 7
// baseline (192.705 us; speedup 1.0000x reference)
//
#include <hip/hip_runtime.h>
#include <cstdint>

// ---------- types & helpers ----------
typedef __attribute__((ext_vector_type(8))) short short8_t;
typedef __attribute__((ext_vector_type(8))) __bf16 bf16x8_t;
typedef __attribute__((ext_vector_type(4))) float f32x4_t;

__device__ __forceinline__ float bf2f(unsigned short u) {
  return __uint_as_float(((unsigned)u) << 16);
}
__device__ __forceinline__ unsigned short f2bf(float f) {  // RNE
  unsigned u = __float_as_uint(f);
  u += 0x7FFFu + ((u >> 16) & 1u);
  return (unsigned short)(u >> 16);
}

// MFMA wrapper: tolerate either builtin signature (short8 or bf16x8 operands).
template <typename V>
__device__ __forceinline__ auto mfma16_impl(V a, V b, f32x4_t c, int)
    -> decltype(__builtin_amdgcn_mfma_f32_16x16x32_bf16(a, b, c, 0, 0, 0)) {
  return __builtin_amdgcn_mfma_f32_16x16x32_bf16(a, b, c, 0, 0, 0);
}
template <typename V>
__device__ __forceinline__ f32x4_t mfma16_impl(V a, V b, f32x4_t c, long) {
  bf16x8_t ab = __builtin_bit_cast(bf16x8_t, a);
  bf16x8_t bb = __builtin_bit_cast(bf16x8_t, b);
  return __builtin_amdgcn_mfma_f32_16x16x32_bf16(ab, bb, c, 0, 0, 0);
}
__device__ __forceinline__ f32x4_t MFMA16(short8_t a, short8_t b, f32x4_t c) {
  return mfma16_impl(a, b, c, 0);
}

#define FRAG_VARS                                                       \
  const int tid = threadIdx.x;                                          \
  const int lane = tid & 63;                                            \
  const int wv = tid >> 6;                                              \
  const int mw = (wv >> 1) << 5;                                        \
  const int nw = (wv & 1) << 5;                                         \
  const int fr = lane & 15;                                             \
  const int fq = lane >> 4;                                             \
  f32x4_t acc00 = {0.f, 0.f, 0.f, 0.f};                                 \
  f32x4_t acc01 = acc00, acc10 = acc00, acc11 = acc00;

// Body sees: ml (local m), nl (local n), vv (float value). Variadic for commas.
#define GEMM_EPILOGUE(...)                                              \
  {                                                                     \
    const f32x4_t accs_[4] = {acc00, acc01, acc10, acc11};              \
    _Pragma("unroll") for (int im_ = 0; im_ < 2; ++im_)                 \
    _Pragma("unroll") for (int jn_ = 0; jn_ < 2; ++jn_) {               \
      f32x4_t aa_ = accs_[im_ * 2 + jn_];                               \
      const int ml0_ = mw + im_ * 16 + fq * 4;                          \
      const int nl = nw + jn_ * 16 + fr;                                \
      _Pragma("unroll") for (int r_ = 0; r_ < 4; ++r_) {                \
        const int ml = ml0_ + r_;                                       \
        const float vv = aa_[r_];                                       \
        __VA_ARGS__;                                                    \
      }                                                                 \
    }                                                                   \
  }

// ---------- async 16B/lane global->LDS (dest = wave-uniform base + lane*16) ----------
#if __has_builtin(__builtin_amdgcn_global_load_lds)
__device__ __forceinline__ void gload16(const void* g, void* lds_wave_base) {
  __builtin_amdgcn_global_load_lds(g, lds_wave_base, 16, 0, 0);
}
#else
__device__ __forceinline__ void gload16(const void* g, void* lds_wave_base) {
  const int lane = threadIdx.x & 63;  // synchronous fallback, same slot mapping
  ((uint4*)lds_wave_base)[lane] = *(const uint4*)g;
}
#endif

// ---------- inline dtype detector (per-block, deterministic, L2-broadcast) ----------
__device__ __forceinline__ int detect_f32(const void* q, int tid, int* sh) {
  const unsigned short* p = (const unsigned short*)q;
  int w = 0;
  for (int i = tid; i < 512; i += 256) {
    float v = bf2f(p[i]);
    float av = fabsf(v);
    if (!(av <= 1e4f) || (v != 0.f && av < 1e-10f)) ++w;  // NaN fails av<=1e4
  }
#pragma unroll
  for (int off = 32; off > 0; off >>= 1) w += __shfl_xor(w, off);
  if ((tid & 63) == 0) sh[tid >> 6] = w;
  __syncthreads();
  return (sh[0] + sh[1] + sh[2] + sh[3]) > 40;  // 1 = inputs are f32
}

// ---------- merged prep: convert (z<9) + weight transpose (z>=9), vectorized ----------
// R17: in bf16 mode, query/src/trg copies (z<3) are DEAD — consumers read the
// raw input buffers directly. Only f32 mode converts them.
struct PrepArgs {
  const void* csrc[9];
  unsigned short* cdst[9];
  int cn[9];
  const void* tsrc[6];
  unsigned short* tdst[6];
  int tK[6];
};

__global__ __launch_bounds__(256) void k_prep(PrepArgs a) {
  __shared__ int shw[4];
  __shared__ unsigned short t[32][33];
  const int z = blockIdx.z;
  if (z < 9) {
    const int n = a.cn[z];  // all n divisible by 8
    const int bid = blockIdx.y * 16 + blockIdx.x;  // 0..767
    if (bid * 256 >= (n >> 2)) return;  // no work in either dtype mode
    const int f32mode = detect_f32(a.csrc[0], threadIdx.x, shw);
    if (z < 3 && !f32mode) return;  // bf16 mode reads raw buffers directly
    const int stride = 768 * 256;
    if (f32mode) {
      const float4* s4 = (const float4*)a.csrc[z];
      ushort4* d4 = (ushort4*)a.cdst[z];
      const int n4 = n >> 2;
      for (int i = bid * 256 + threadIdx.x; i < n4; i += stride) {
        float4 v = s4[i];
        ushort4 o;
        o.x = f2bf(v.x); o.y = f2bf(v.y); o.z = f2bf(v.z); o.w = f2bf(v.w);
        d4[i] = o;
      }
    } else {
      const uint4* s8 = (const uint4*)a.csrc[z];
      uint4* d8 = (uint4*)a.cdst[z];
      const int n8 = n >> 3;
      for (int i = bid * 256 + threadIdx.x; i < n8; i += stride) d8[i] = s8[i];
    }
  } else {
    const int w = z - 9;
    const int K = a.tK[w];
    const int k0 = blockIdx.y * 32, n0 = blockIdx.x * 32;
    if (k0 >= K) return;  // hoisted: skip detector for out-of-range tiles
    const int f32mode = detect_f32(a.csrc[0], threadIdx.x, shw);
    const int r = threadIdx.x >> 3;        // 0..31
    const int c4 = (threadIdx.x & 7) * 4;  // 0,4,..,28
    if (f32mode) {
      const float* s = (const float*)a.tsrc[w];
      float4 v = *(const float4*)&s[(size_t)(k0 + r) * 512 + n0 + c4];
      t[r][c4] = f2bf(v.x); t[r][c4 + 1] = f2bf(v.y);
      t[r][c4 + 2] = f2bf(v.z); t[r][c4 + 3] = f2bf(v.w);
    } else {
      const unsigned short* s = (const unsigned short*)a.tsrc[w];
      ushort4 v = *(const ushort4*)&s[(size_t)(k0 + r) * 512 + n0 + c4];
      t[r][c4] = v.x; t[r][c4 + 1] = v.y; t[r][c4 + 2] = v.z; t[r][c4 + 3] = v.w;
    }
    __syncthreads();
    unsigned short* d = a.tdst[w];
    ushort4 o;
    o.x = t[c4][r]; o.y = t[c4 + 1][r]; o.z = t[c4 + 2][r]; o.w = t[c4 + 3][r];
    *(ushort4*)&d[(size_t)(n0 + r) * K + k0 + c4] = o;
  }
}

// ---------- five projections ----------
// R18: XCD-local tile map. XCD = linear blockIdx % 8; tiles sharing an A
// row-panel must be congruent mod 8. op0: id = by + 32*bx (by=id&31 -> id%8
// = by%8). ops1-4: r2 = by + 16*bx (by%8 = r2%8). So all bx-sharers of a
// given by land on ONE XCD -> A panel fetched into one L2, not eight.
// Also: W prefetch issued BEFORE detect_f32 (dtype-independent pointer), so
// the detector's ~600cy dependent-load chain overlaps the first W loads.
struct ProjArgs {
  const unsigned short* A[5];
  const void* rawA[5];
  const unsigned short* W[5];
  const unsigned short* bias[5];
  unsigned short* out[5];
  const void* rawq;
};

__global__ __launch_bounds__(256) void k_proj(ProjArgs args) {
  __shared__ int shw[4];
  const int id = blockIdx.x;  // 0..767, all live
  int op, by, bx;
  if (id < 256) {
    op = 0; by = id & 31; bx = id >> 5;
  } else {
    int r2 = id - 256;
    op = 1 + (r2 >> 7); r2 &= 127; by = r2 & 15; bx = r2 >> 4;
  }
  const int m0 = by * 64, n0 = bx * 64;
  const unsigned short* W = args.W[op];
  FRAG_VARS;
  __shared__ __align__(16) unsigned short sm[2][2][64 * 64];  // [buf][A=0/B=1] 32KB
  const int srow = lane >> 3;                       // 0..7 within wave's 8 rows
  const int scol = ((lane & 7) ^ srow) * 8;         // swizzled global elem offset
#pragma unroll
  for (int h = 0; h < 2; ++h) {  // W first: pointer known pre-detect
    const int row = h * 32 + wv * 8;
    gload16(&W[(size_t)(n0 + row + srow) * 1024 + scol], &sm[0][1][row * 64]);
  }
  const int f32mode = detect_f32(args.rawq, tid, shw);
  const unsigned short* A =
      f32mode ? args.A[op] : (const unsigned short*)args.rawA[op];
#pragma unroll
  for (int h = 0; h < 2; ++h) {
    const int row = h * 32 + wv * 8;
    gload16(&A[(size_t)(m0 + row + srow) * 1024 + scol], &sm[0][0][row * 64]);
  }
  const int cs0 = ((fq) ^ (fr & 7)) * 8;        // ks=0 slot
  const int cs1 = ((4 + fq) ^ (fr & 7)) * 8;    // ks=1 slot
  for (int kc = 0; kc < 16; ++kc) {
    const int cur = kc & 1;
    __syncthreads();
    if (kc + 1 < 16) {
      const int nxt = cur ^ 1;
      const int k0 = (kc + 1) * 64;
#pragma unroll
      for (int h = 0; h < 2; ++h) {
        const int row = h * 32 + wv * 8;
        gload16(&A[(size_t)(m0 + row + srow) * 1024 + k0 + scol], &sm[nxt][0][row * 64]);
        gload16(&W[(size_t)(n0 + row + srow) * 1024 + k0 + scol], &sm[nxt][1][row * 64]);
      }
    }
    const unsigned short* Ab = sm[cur][0];
    const unsigned short* Bb = sm[cur][1];
    {
      short8_t a0 = *(const short8_t*)&Ab[(mw + fr) * 64 + cs0];
      short8_t a1 = *(const short8_t*)&Ab[(mw + 16 + fr) * 64 + cs0];
      short8_t b0 = *(const short8_t*)&Bb[(nw + fr) * 64 + cs0];
      short8_t b1 = *(const short8_t*)&Bb[(nw + 16 + fr) * 64 + cs0];
      acc00 = MFMA16(a0, b0, acc00);
      acc01 = MFMA16(a0, b1, acc01);
      acc10 = MFMA16(a1, b0, acc10);
      acc11 = MFMA16(a1, b1, acc11);
    }
    {
      short8_t a0 = *(const short8_t*)&Ab[(mw + fr) * 64 + cs1];
      short8_t a1 = *(const short8_t*)&Ab[(mw + 16 + fr) * 64 + cs1];
      short8_t b0 = *(const short8_t*)&Bb[(nw + fr) * 64 + cs1];
      short8_t b1 = *(const short8_t*)&Bb[(nw + 16 + fr) * 64 + cs1];
      acc00 = MFMA16(a0, b0, acc00);
      acc01 = MFMA16(a0, b1, acc01);
      acc10 = MFMA16(a1, b0, acc10);
      acc11 = MFMA16(a1, b1, acc11);
    }
  }
  const float scale = (op == 0) ? 0.044194173824159216f : 1.0f;
  const unsigned short* bias = args.bias[op];
  unsigned short* out = args.out[op];
  GEMM_EPILOGUE({
    const float v = (vv + bf2f(bias[n0 + nl])) * scale;
    const int m = m0 + ml;
    const int n = n0 + nl;
    if (op < 3) {
      out[(size_t)m * 512 + n] = f2bf(v);
    } else {
      const int bb = m >> 6;
      const int ss = m & 63;
      out[(size_t)bb * 32768 + (size_t)n * 64 + ss] = f2bf(v);
    }
  });
}

// ---------- scores: fused exp / row-partials; R18: XCD-local grid + coalesced store ----------
// Grid (32, 32): x = b*2+mhalf (fast axis -> all 32 sx-blocks sharing a q/tk
// panel are congruent mod 8 -> one XCD's L2). Epilogue: exp -> XOR-swizzled
// LDS stage (reusing dead qS, conflict-free) -> 64B/thread coalesced drain
// (replaces 64 scattered u16 global stores per thread).
__global__ __launch_bounds__(256) void k_scores(
    const unsigned short* __restrict__ qs, const unsigned short* __restrict__ skey,
    const unsigned short* __restrict__ tkey, unsigned short* __restrict__ scores,
    float* __restrict__ Zp) {
  const int x = blockIdx.x;   // 0..31: b*2 + mhalf
  const int b = x >> 1;
  const int m0 = (x & 1) * 64;
  const int sx = blockIdx.y;  // 0..31: s = sx*2 + {0,1}
  const int tid = threadIdx.x;
  const int lane = tid & 63;
  const int wv = tid >> 6;
  const int mw = (wv >> 1) << 5;
  const int nw = (wv & 1) << 5;
  const int fr = lane & 15;
  const int fq = lane >> 4;
  __shared__ __align__(16) unsigned short qS[2][64 * 64];   // 16KB (epilogue scratch)
  __shared__ __align__(16) unsigned short tkS[2][64 * 64];  // 16KB
  __shared__ __align__(16) unsigned short skL[1024];        // 2KB: 2 s-rows x 512
  f32x4_t acc[2][4];
#pragma unroll
  for (int s = 0; s < 2; ++s)
#pragma unroll
    for (int i = 0; i < 4; ++i) acc[s][i] = (f32x4_t){0.f, 0.f, 0.f, 0.f};
  const unsigned short* qb = qs + ((size_t)b * 128 + m0) * 512;
  const unsigned short* tkb = tkey + (size_t)b * 64 * 512;
  const unsigned short* skb = skey + ((size_t)b * 64 + sx * 2) * 512;
  if (tid < 128) *(uint4*)&skL[tid * 8] = *(const uint4*)&skb[tid * 8];
  const int srow = lane >> 3;
  const int scol = ((lane & 7) ^ srow) * 8;
#pragma unroll
  for (int h = 0; h < 2; ++h) {
    const int row = h * 32 + wv * 8;
    gload16(&qb[(size_t)(row + srow) * 512 + scol], &qS[0][row * 64]);
    gload16(&tkb[(size_t)(row + srow) * 512 + scol], &tkS[0][row * 64]);
  }
  const int cs0 = ((fq) ^ (fr & 7)) * 8;
  const int cs1 = ((4 + fq) ^ (fr & 7)) * 8;
  for (int kc = 0; kc < 8; ++kc) {
    const int cur = kc & 1;
    __syncthreads();  // drains prev prefetch (overlapped with prev compute)
    if (kc + 1 < 8) {
      const int k0 = (kc + 1) * 64;
      const int nxt = cur ^ 1;
#pragma unroll
      for (int h = 0; h < 2; ++h) {
        const int row = h * 32 + wv * 8;
        gload16(&qb[(size_t)(row + srow) * 512 + k0 + scol], &qS[nxt][row * 64]);
        gload16(&tkb[(size_t)(row + srow) * 512 + k0 + scol], &tkS[nxt][row * 64]);
      }
    }
#pragma unroll
    for (int ks = 0; ks < 2; ++ks) {
      const int cs = ks ? cs1 : cs0;
      short8_t a0 = *(const short8_t*)&qS[cur][(mw + fr) * 64 + cs];
      short8_t a1 = *(const short8_t*)&qS[cur][(mw + 16 + fr) * 64 + cs];
      uint4 tq[2];
      tq[0] = *(const uint4*)&tkS[cur][(nw + fr) * 64 + cs];
      tq[1] = *(const uint4*)&tkS[cur][(nw + 16 + fr) * 64 + cs];
      float tlo[2][4], thi[2][4];
#pragma unroll
      for (int h = 0; h < 2; ++h) {
        const unsigned* tw = (const unsigned*)&tq[h];
#pragma unroll
        for (int j = 0; j < 4; ++j) {
          tlo[h][j] = __uint_as_float(tw[j] << 16);
          thi[h][j] = __uint_as_float(tw[j] & 0xffff0000u);
        }
      }
      const int koff = kc * 64 + ks * 32 + fq * 8;  // logical k for sk (broadcast)
#pragma unroll
      for (int s = 0; s < 2; ++s) {
        uint4 skq = *(const uint4*)&skL[s * 512 + koff];
        const unsigned* sw = (const unsigned*)&skq;
        union { short8_t v; unsigned w[4]; } b0, b1;
#pragma unroll
        for (int j = 0; j < 4; ++j) {
          const float slo = __uint_as_float(sw[j] << 16);
          const float shi = __uint_as_float(sw[j] & 0xffff0000u);
          b0.w[j] = __builtin_amdgcn_perm(__float_as_uint(thi[0][j] * shi),
                                          __float_as_uint(tlo[0][j] * slo), 0x07060302);
          b1.w[j] = __builtin_amdgcn_perm(__float_as_uint(thi[1][j] * shi),
                                          __float_as_uint(tlo[1][j] * slo), 0x07060302);
        }
        acc[s][0] = MFMA16(a0, b0.v, acc[s][0]);
        acc[s][1] = MFMA16(a0, b1.v, acc[s][1]);
        acc[s][2] = MFMA16(a1, b0.v, acc[s][2]);
        acc[s][3] = MFMA16(a1, b1.v, acc[s][3]);
      }
    }
  }
  // ---- epilogue: exp -> swizzled LDS stage -> coalesced drain + row sums ----
  __syncthreads();  // all LDS reads of the K-loop done; qS becomes scratch
  unsigned short* es = &qS[0][0];  // [64][128] u16, col XOR-swizzled by row
  float rs0[4] = {0.f, 0.f, 0.f, 0.f};
  float rs1[4] = {0.f, 0.f, 0.f, 0.f};
#pragma unroll
  for (int s = 0; s < 2; ++s)
#pragma unroll
    for (int im = 0; im < 2; ++im)
#pragma unroll
      for (int jn = 0; jn < 2; ++jn) {
        const int cc = s * 64 + nw + jn * 16 + fr;
#pragma unroll
        for (int r = 0; r < 4; ++r) {
          const int row = mw + im * 16 + fq * 4 + r;
          const unsigned short eb = f2bf(__expf(acc[s][im * 2 + jn][r]));
          es[row * 128 + (cc ^ ((row & 7) << 4))] = eb;
          const float e = bf2f(eb);  // sum the SAME rounded value ctx reads
          if (im == 0) rs0[r] += e; else rs1[r] += e;
        }
      }
  // per-row partial sums -> Zp[row][slot], slot = sx*2 + t-half (race-free)
  const int zslot = sx * 2 + (nw >> 5);
#pragma unroll
  for (int im = 0; im < 2; ++im)
#pragma unroll
    for (int r = 0; r < 4; ++r) {
      float p = (im == 0) ? rs0[r] : rs1[r];
      p += __shfl_xor(p, 1);
      p += __shfl_xor(p, 2);
      p += __shfl_xor(p, 4);
      p += __shfl_xor(p, 8);
      if (fr == 0) {
        const int row = m0 + mw + im * 16 + fq * 4 + r;
        Zp[((size_t)b * 128 + row) * 64 + zslot] = p;
      }
    }
  __syncthreads();
  // drain: thread -> (row = tid>>2, 32 u16 at c0=(tid&3)*32), 64B contiguous global
  {
    const int row = tid >> 2;
    const int c0 = (tid & 3) * 32;
    const int sw = (row & 7) << 4;
    unsigned short* dst =
        scores + ((size_t)b * 128 + m0 + row) * 4096 + sx * 128 + c0;
    uint4 v[4];
#pragma unroll
    for (int g = 0; g < 2; ++g) {  // 16-u16 granules stay contiguous under XOR
      const uint4* src = (const uint4*)&es[row * 128 + ((c0 + g * 16) ^ sw)];
      v[g * 2] = src[0];
      v[g * 2 + 1] = src[1];
    }
#pragma unroll
    for (int g = 0; g < 4; ++g) ((uint4*)dst)[g] = v[g];
  }
}

// ---------- ctx: fused s=0..63 + softmax normalization (XCD-local by luck) ----------
__global__ __launch_bounds__(512) void k_ctx(
    const unsigned short* __restrict__ p, const unsigned short* __restrict__ svT,
    const unsigned short* __restrict__ tvT, unsigned short* __restrict__ ctx,
    const float* __restrict__ Zp) {
  const int b = blockIdx.x >> 1;
  const int m0 = (blockIdx.x & 1) * 64;
  const int n0 = blockIdx.y * 64;
  const int tid = threadIdx.x;
  const int lane = tid & 63;
  const int wv = tid >> 6;           // 0..7
  const int sgrp = wv >> 2;          // 0/1: which s-half this wave-group does
  const int mw = ((wv >> 1) & 1) << 5;
  const int nw = (wv & 1) << 5;
  const int fr = lane & 15;
  const int fq = lane >> 4;
  f32x4_t acc00 = {0.f, 0.f, 0.f, 0.f};
  f32x4_t acc01 = acc00, acc10 = acc00, acc11 = acc00;
  __shared__ __align__(16) unsigned short smem[2 * 64 * 72];  // 18.4KB
  __shared__ float zrow[64];
  unsigned short* tvl = smem;             // [64][72] t-major value tile
  unsigned short* svl = smem + 64 * 72;   // [64 n][72 pad] s-vector tile
  {
    const unsigned short* tvb = tvT + (size_t)b * 32768 + (size_t)n0 * 64;
    const unsigned short* svb = svT + (size_t)b * 32768 + (size_t)n0 * 64;
    const int r = tid >> 3, c = (tid & 7) * 8;  // 512 threads cover 64x64 once
    *(uint4*)&tvl[r * 72 + c] = *(const uint4*)&tvb[(size_t)r * 64 + c];
    *(uint4*)&svl[r * 72 + c] = *(const uint4*)&svb[(size_t)r * 64 + c];
  }
  if (tid < 64) {  // denominator: sum the 64 per-row partials (L2-hot, 1KB/row)
    const f32x4_t* zp = (const f32x4_t*)(Zp + ((size_t)b * 128 + m0 + tid) * 64);
    f32x4_t s4 = zp[0];
#pragma unroll
    for (int i = 1; i < 16; ++i) {
      const f32x4_t v = zp[i];
      s4[0] += v[0]; s4[1] += v[1]; s4[2] += v[2]; s4[3] += v[3];
    }
    zrow[tid] = s4[0] + s4[1] + s4[2] + s4[3];
  }
  __syncthreads();
  short8_t bv[2][2];
  bv[0][0] = *(const short8_t*)&tvl[(nw + fr) * 72 + fq * 8];
  bv[0][1] = *(const short8_t*)&tvl[(nw + fr) * 72 + 32 + fq * 8];
  bv[1][0] = *(const short8_t*)&tvl[(nw + 16 + fr) * 72 + fq * 8];
  bv[1][1] = *(const short8_t*)&tvl[(nw + 16 + fr) * 72 + 32 + fq * 8];
  const unsigned short* ar0 =
      p + ((size_t)b * 128 + m0 + mw + fr) * 4096 + sgrp * 2048 + fq * 8;
  const unsigned short* ar1 = ar0 + (size_t)16 * 4096;
  uint4 pa[4][2][2];  // 4-deep register prefetch
#pragma unroll
  for (int d = 0; d < 4; ++d) {
    const int off = d * 64;
    pa[d][0][0] = *(const uint4*)(ar0 + off);
    pa[d][0][1] = *(const uint4*)(ar0 + off + 32);
    pa[d][1][0] = *(const uint4*)(ar1 + off);
    pa[d][1][1] = *(const uint4*)(ar1 + off + 32);
  }
#pragma unroll 4
  for (int s = 0; s < 32; ++s) {
    const int sl = s & 3;  // static under unroll-4 (no scratch)
    short8_t a00 = __builtin_bit_cast(short8_t, pa[sl][0][0]);
    short8_t a01 = __builtin_bit_cast(short8_t, pa[sl][0][1]);
    short8_t a10 = __builtin_bit_cast(short8_t, pa[sl][1][0]);
    short8_t a11 = __builtin_bit_cast(short8_t, pa[sl][1][1]);
    if (s + 4 < 32) {
      const int off = (s + 4) * 64;
      pa[sl][0][0] = *(const uint4*)(ar0 + off);
      pa[sl][0][1] = *(const uint4*)(ar0 + off + 32);
      pa[sl][1][0] = *(const uint4*)(ar1 + off);
      pa[sl][1][1] = *(const uint4*)(ar1 + off + 32);
    }
    const f32x4_t z4 = {0.f, 0.f, 0.f, 0.f};
    f32x4_t M00 = MFMA16(a00, bv[0][0], z4);
    M00 = MFMA16(a01, bv[0][1], M00);
    f32x4_t M01 = MFMA16(a00, bv[1][0], z4);
    M01 = MFMA16(a01, bv[1][1], M01);
    f32x4_t M10 = MFMA16(a10, bv[0][0], z4);
    M10 = MFMA16(a11, bv[0][1], M10);
    f32x4_t M11 = MFMA16(a10, bv[1][0], z4);
    M11 = MFMA16(a11, bv[1][1], M11);
    const float sv0 = bf2f(svl[(nw + fr) * 72 + sgrp * 32 + s]);
    const float sv1 = bf2f(svl[(nw + 16 + fr) * 72 + sgrp * 32 + s]);
#pragma unroll
    for (int r = 0; r < 4; ++r) {
      acc00[r] += sv0 * M00[r];
      acc01[r] += sv1 * M01[r];
      acc10[r] += sv0 * M10[r];
      acc11[r] += sv1 * M11[r];
    }
  }
  __syncthreads();  // all waves done reading svl/tvl; reuse smem as f32 scratch
  float* shf = (float*)smem;  // 16KB <= 18.4KB (zrow is separate, preserved)
  const int roff = (wv & 3) * 1024 + lane * 4;
  if (sgrp == 1) {
    *(f32x4_t*)&shf[roff] = acc00;
    *(f32x4_t*)&shf[roff + 256] = acc01;
    *(f32x4_t*)&shf[roff + 512] = acc10;
    *(f32x4_t*)&shf[roff + 768] = acc11;
  }
  __syncthreads();
  if (sgrp == 0) {
    acc00 += *(const f32x4_t*)&shf[roff];
    acc01 += *(const f32x4_t*)&shf[roff + 256];
    acc10 += *(const f32x4_t*)&shf[roff + 512];
    acc11 += *(const f32x4_t*)&shf[roff + 768];
    unsigned short* out = ctx + ((size_t)b * 128 + m0) * 512 + n0;
    GEMM_EPILOGUE({ out[(size_t)ml * 512 + nl] = f2bf(vv / zrow[ml]); });
  }
}

// ---------- out = relu(concat(query, ctx) @ Wo + bo) ----------
// R18: grid swapped to (32 m-tiles, 8 n-tiles) -> same-m blocks congruent
// mod 8 -> query/ctx row-panels XCD-local. W prefetch issued pre-detect.
__global__ __launch_bounds__(256) void k_out(
    const unsigned short* __restrict__ query, const unsigned short* __restrict__ ctx,
    const unsigned short* __restrict__ WoT, const unsigned short* __restrict__ bo,
    void* __restrict__ outv, const void* __restrict__ rawq) {
  __shared__ int shw[4];
  const int m0 = blockIdx.x * 64, n0 = blockIdx.y * 64;
  FRAG_VARS;
  __shared__ __align__(16) unsigned short sm[2][2][64 * 128];  // [buf][A/B] 64KB
  const int srow4 = lane >> 4;   // 0..3: row within 4-row gload window
  const int c8 = lane & 15;      // 16B-chunk column id
  auto issueW = [&](int buf, int kc) {
#pragma unroll
    for (int g = 0; g < 4; ++g) {
      const int R0 = wv * 16 + g * 4;
      const int row = R0 + srow4;
      const int col = (c8 ^ ((g * 4 + srow4) & 7)) * 8;
      gload16(&WoT[(size_t)(n0 + row) * 1536 + kc * 128 + col], &sm[buf][1][R0 * 128]);
    }
  };
  issueW(0, 0);  // dtype-independent: overlaps the detector
  const int f32mode = detect_f32(rawq, tid, shw);
  const unsigned short* qsrc = f32mode ? query : (const unsigned short*)rawq;
  auto issueA = [&](int buf, int kc) {
    const unsigned short* abase;
    size_t astr;
    int kb;
    if (kc < 8) { abase = qsrc + (size_t)m0 * 1024; astr = 1024; kb = kc * 128; }
    else { abase = ctx + (size_t)m0 * 512; astr = 512; kb = (kc - 8) * 128; }
#pragma unroll
    for (int g = 0; g < 4; ++g) {
      const int R0 = wv * 16 + g * 4;
      const int row = R0 + srow4;
      const int col = (c8 ^ ((g * 4 + srow4) & 7)) * 8;
      gload16(&abase[(size_t)row * astr + kb + col], &sm[buf][0][R0 * 128]);
    }
  };
  issueA(0, 0);
  for (int kc = 0; kc < 12; ++kc) {
    const int cur = kc & 1;
    __syncthreads();
    if (kc + 1 < 12) { issueA(cur ^ 1, kc + 1); issueW(cur ^ 1, kc + 1); }
    const unsigned short* Ab = sm[cur][0];
    const unsigned short* Bb = sm[cur][1];
#pragma unroll
    for (int ks = 0; ks < 4; ++ks) {
      const int sl = ((ks * 4 + fq) ^ (fr & 7)) * 8;
      short8_t a0 = *(const short8_t*)&Ab[(mw + fr) * 128 + sl];
      short8_t a1 = *(const short8_t*)&Ab[(mw + 16 + fr) * 128 + sl];
      short8_t b0 = *(const short8_t*)&Bb[(nw + fr) * 128 + sl];
      short8_t b1 = *(const short8_t*)&Bb[(nw + 16 + fr) * 128 + sl];
      acc00 = MFMA16(a0, b0, acc00);
      acc01 = MFMA16(a0, b1, acc01);
      acc10 = MFMA16(a1, b0, acc10);
      acc11 = MFMA16(a1, b1, acc11);
    }
  }
  GEMM_EPILOGUE({
    float v = fmaxf(vv + bf2f(bo[n0 + nl]), 0.f);
    const size_t idx = (size_t)(m0 + ml) * 512 + n0 + nl;
    if (f32mode)
      ((float*)outv)[idx] = v;
    else
      ((unsigned short*)outv)[idx] = f2bf(v);
  });
}

// ---------- launch ----------
extern "C" void kernel_launch(void* const* d_in, const int* in_sizes, int n_in,
                              void* d_out, int out_size, void* d_ws, size_t ws_size,
                              hipStream_t stream) {
  const void* query = d_in[0];
  const void* src = d_in[1];
  const void* trg = d_in[2];
  const void* Wq = d_in[3];
  const void* bq = d_in[4];
  const void* Ws = d_in[5];
  const void* bs = d_in[6];
  const void* Wt = d_in[7];
  const void* bt = d_in[8];
  const void* Wsv = d_in[9];
  const void* bsv = d_in[10];
  const void* Wtv = d_in[11];
  const void* btv = d_in[12];
  const void* Wo = d_in[13];
  const void* bo = d_in[14];

  char* ws = (char*)d_ws;
  size_t off = 0;
  auto alloc = [&](size_t bytes) {
    char* ptr = ws + off;
    off = (off + bytes + 255) & ~(size_t)255;
    return ptr;
  };
  unsigned short* qc = (unsigned short*)alloc((size_t)2048 * 1024 * 2);
  unsigned short* srcc = (unsigned short*)alloc((size_t)1024 * 1024 * 2);
  unsigned short* trgc = (unsigned short*)alloc((size_t)1024 * 1024 * 2);
  unsigned short* biasc = (unsigned short*)alloc((size_t)6 * 512 * 2);
  unsigned short* wT = (unsigned short*)alloc((size_t)5 * 524288 * 2);
  unsigned short* woT = (unsigned short*)alloc((size_t)512 * 1536 * 2);
  unsigned short* q_s = (unsigned short*)alloc((size_t)2048 * 512 * 2);
  unsigned short* s_key = (unsigned short*)alloc((size_t)1024 * 512 * 2);
  unsigned short* t_key = (unsigned short*)alloc((size_t)1024 * 512 * 2);
  unsigned short* sv_T = (unsigned short*)alloc((size_t)16 * 512 * 64 * 2);
  unsigned short* tv_T = (unsigned short*)alloc((size_t)16 * 512 * 64 * 2);
  unsigned short* scores = (unsigned short*)alloc((size_t)2048 * 4096 * 2);
  unsigned short* ctx = (unsigned short*)alloc((size_t)2048 * 512 * 2);
  float* Zp = (float*)alloc((size_t)2048 * 64 * 4);  // [row][64 slots]
  (void)ws_size; (void)in_sizes; (void)n_in; (void)out_size;

  PrepArgs pr;
  pr.csrc[0] = query; pr.csrc[1] = src; pr.csrc[2] = trg;
  pr.csrc[3] = bq; pr.csrc[4] = bs; pr.csrc[5] = bt;
  pr.csrc[6] = bsv; pr.csrc[7] = btv; pr.csrc[8] = bo;
  pr.cdst[0] = qc; pr.cdst[1] = srcc; pr.cdst[2] = trgc;
  for (int i = 0; i < 6; ++i) pr.cdst[3 + i] = biasc + i * 512;
  pr.cn[0] = 2048 * 1024; pr.cn[1] = 1024 * 1024; pr.cn[2] = 1024 * 1024;
  for (int i = 0; i < 6; ++i) pr.cn[3 + i] = 512;
  pr.tsrc[0] = Wq; pr.tsrc[1] = Ws; pr.tsrc[2] = Wt;
  pr.tsrc[3] = Wsv; pr.tsrc[4] = Wtv; pr.tsrc[5] = Wo;
  for (int i = 0; i < 5; ++i) { pr.tdst[i] = wT + (size_t)i * 524288; pr.tK[i] = 1024; }
  pr.tdst[5] = woT; pr.tK[5] = 1536;
  hipLaunchKernelGGL(k_prep, dim3(16, 48, 15), dim3(256), 0, stream, pr);

  ProjArgs pa;
  pa.A[0] = qc; pa.A[1] = srcc; pa.A[2] = trgc; pa.A[3] = srcc; pa.A[4] = trgc;
  pa.rawA[0] = query; pa.rawA[1] = src; pa.rawA[2] = trg;
  pa.rawA[3] = src; pa.rawA[4] = trg;
  for (int i = 0; i < 5; ++i) pa.W[i] = wT + (size_t)i * 524288;
  for (int i = 0; i < 5; ++i) pa.bias[i] = biasc + i * 512;
  pa.out[0] = q_s; pa.out[1] = s_key; pa.out[2] = t_key; pa.out[3] = sv_T; pa.out[4] = tv_T;
  pa.rawq = query;
  hipLaunchKernelGGL(k_proj, dim3(768), dim3(256), 0, stream, pa);

  hipLaunchKernelGGL(k_scores, dim3(32, 32, 1), dim3(256), 0, stream, q_s, s_key,
                     t_key, scores, Zp);
  hipLaunchKernelGGL(k_ctx, dim3(32, 8), dim3(512), 0, stream, scores, sv_T, tv_T,
                     ctx, Zp);
  hipLaunchKernelGGL(k_out, dim3(32, 8, 1), dim3(256), 0, stream, qc, ctx, woT,
                     biasc + 5 * 512, d_out, query);
}

// Round 8
// 184.947 us; speedup vs baseline: 1.0419x; 1.0419x over previous
//
#include <hip/hip_runtime.h>
#include <cstdint>

// ---------- types & helpers ----------
typedef __attribute__((ext_vector_type(8))) short short8_t;
typedef __attribute__((ext_vector_type(8))) __bf16 bf16x8_t;
typedef __attribute__((ext_vector_type(4))) float f32x4_t;

__device__ __forceinline__ float bf2f(unsigned short u) {
  return __uint_as_float(((unsigned)u) << 16);
}
__device__ __forceinline__ unsigned short f2bf(float f) {  // RNE
  unsigned u = __float_as_uint(f);
  u += 0x7FFFu + ((u >> 16) & 1u);
  return (unsigned short)(u >> 16);
}

// MFMA wrapper: tolerate either builtin signature (short8 or bf16x8 operands).
template <typename V>
__device__ __forceinline__ auto mfma16_impl(V a, V b, f32x4_t c, int)
    -> decltype(__builtin_amdgcn_mfma_f32_16x16x32_bf16(a, b, c, 0, 0, 0)) {
  return __builtin_amdgcn_mfma_f32_16x16x32_bf16(a, b, c, 0, 0, 0);
}
template <typename V>
__device__ __forceinline__ f32x4_t mfma16_impl(V a, V b, f32x4_t c, long) {
  bf16x8_t ab = __builtin_bit_cast(bf16x8_t, a);
  bf16x8_t bb = __builtin_bit_cast(bf16x8_t, b);
  return __builtin_amdgcn_mfma_f32_16x16x32_bf16(ab, bb, c, 0, 0, 0);
}
__device__ __forceinline__ f32x4_t MFMA16(short8_t a, short8_t b, f32x4_t c) {
  return mfma16_impl(a, b, c, 0);
}

#define FRAG_VARS                                                       \
  const int tid = threadIdx.x;                                          \
  const int lane = tid & 63;                                            \
  const int wv = tid >> 6;                                              \
  const int mw = (wv >> 1) << 5;                                        \
  const int nw = (wv & 1) << 5;                                         \
  const int fr = lane & 15;                                             \
  const int fq = lane >> 4;                                             \
  f32x4_t acc00 = {0.f, 0.f, 0.f, 0.f};                                 \
  f32x4_t acc01 = acc00, acc10 = acc00, acc11 = acc00;

// Body sees: ml (local m), nl (local n), vv (float value). Variadic for commas.
#define GEMM_EPILOGUE(...)                                              \
  {                                                                     \
    const f32x4_t accs_[4] = {acc00, acc01, acc10, acc11};              \
    _Pragma("unroll") for (int im_ = 0; im_ < 2; ++im_)                 \
    _Pragma("unroll") for (int jn_ = 0; jn_ < 2; ++jn_) {               \
      f32x4_t aa_ = accs_[im_ * 2 + jn_];                               \
      const int ml0_ = mw + im_ * 16 + fq * 4;                          \
      const int nl = nw + jn_ * 16 + fr;                                \
      _Pragma("unroll") for (int r_ = 0; r_ < 4; ++r_) {                \
        const int ml = ml0_ + r_;                                       \
        const float vv = aa_[r_];                                       \
        __VA_ARGS__;                                                    \
      }                                                                 \
    }                                                                   \
  }

// ---------- async 16B/lane global->LDS (dest = wave-uniform base + lane*16) ----------
#if __has_builtin(__builtin_amdgcn_global_load_lds)
__device__ __forceinline__ void gload16(const void* g, void* lds_wave_base) {
  __builtin_amdgcn_global_load_lds(g, lds_wave_base, 16, 0, 0);
}
#else
__device__ __forceinline__ void gload16(const void* g, void* lds_wave_base) {
  const int lane = threadIdx.x & 63;  // synchronous fallback, same slot mapping
  ((uint4*)lds_wave_base)[lane] = *(const uint4*)g;
}
#endif

// ---------- inline dtype detector (per-block, deterministic, L2-broadcast) ----------
__device__ __forceinline__ int detect_f32(const void* q, int tid, int* sh) {
  const unsigned short* p = (const unsigned short*)q;
  int w = 0;
  for (int i = tid; i < 512; i += 256) {
    float v = bf2f(p[i]);
    float av = fabsf(v);
    if (!(av <= 1e4f) || (v != 0.f && av < 1e-10f)) ++w;  // NaN fails av<=1e4
  }
#pragma unroll
  for (int off = 32; off > 0; off >>= 1) w += __shfl_xor(w, off);
  if ((tid & 63) == 0) sh[tid >> 6] = w;
  __syncthreads();
  return (sh[0] + sh[1] + sh[2] + sh[3]) > 40;  // 1 = inputs are f32
}

// ---------- merged prep: convert (z<9) + weight transpose (z>=9) ----------
// R19: block (z=0,bid=0) publishes the dtype flag to the workspace; later
// kernels read it (same-stream ordering; rewritten after each re-poison).
// Convert grid trimmed to 256 blocks (pre-detect, grid-uniform) — f32 mode
// covers via grid-stride; bf16 mode skips ~2300 detector runs.
struct PrepArgs {
  const void* csrc[9];
  unsigned short* cdst[9];
  int cn[9];
  const void* tsrc[6];
  unsigned short* tdst[6];
  int tK[6];
  int* flag;
};

__global__ __launch_bounds__(256) void k_prep(PrepArgs a) {
  __shared__ int shw[4];
  __shared__ unsigned short t[32][33];
  const int z = blockIdx.z;
  if (z < 9) {
    const int n = a.cn[z];  // all n divisible by 8
    const int bid = blockIdx.y * 16 + blockIdx.x;  // 0..767
    if (z < 3 && bid >= 256) return;               // trimmed convert grid
    if (bid * 256 >= (n >> 2)) return;  // no work in either dtype mode
    const int f32mode = detect_f32(a.csrc[0], threadIdx.x, shw);
    if (z == 0 && bid == 0 && threadIdx.x == 0) *a.flag = f32mode;
    if (z < 3 && !f32mode) return;  // bf16 mode reads raw buffers directly
    const int stride = 256 * 256;
    if (f32mode) {
      const float4* s4 = (const float4*)a.csrc[z];
      ushort4* d4 = (ushort4*)a.cdst[z];
      const int n4 = n >> 2;
      for (int i = bid * 256 + threadIdx.x; i < n4; i += stride) {
        float4 v = s4[i];
        ushort4 o;
        o.x = f2bf(v.x); o.y = f2bf(v.y); o.z = f2bf(v.z); o.w = f2bf(v.w);
        d4[i] = o;
      }
    } else {
      const uint4* s8 = (const uint4*)a.csrc[z];
      uint4* d8 = (uint4*)a.cdst[z];
      const int n8 = n >> 3;
      for (int i = bid * 256 + threadIdx.x; i < n8; i += stride) d8[i] = s8[i];
    }
  } else {
    const int w = z - 9;
    const int K = a.tK[w];
    const int k0 = blockIdx.y * 32, n0 = blockIdx.x * 32;
    if (k0 >= K) return;  // hoisted: skip detector for out-of-range tiles
    const int f32mode = detect_f32(a.csrc[0], threadIdx.x, shw);
    const int r = threadIdx.x >> 3;        // 0..31
    const int c4 = (threadIdx.x & 7) * 4;  // 0,4,..,28
    if (f32mode) {
      const float* s = (const float*)a.tsrc[w];
      float4 v = *(const float4*)&s[(size_t)(k0 + r) * 512 + n0 + c4];
      t[r][c4] = f2bf(v.x); t[r][c4 + 1] = f2bf(v.y);
      t[r][c4 + 2] = f2bf(v.z); t[r][c4 + 3] = f2bf(v.w);
    } else {
      const unsigned short* s = (const unsigned short*)a.tsrc[w];
      ushort4 v = *(const ushort4*)&s[(size_t)(k0 + r) * 512 + n0 + c4];
      t[r][c4] = v.x; t[r][c4 + 1] = v.y; t[r][c4 + 2] = v.z; t[r][c4 + 3] = v.w;
    }
    __syncthreads();
    unsigned short* d = a.tdst[w];
    ushort4 o;
    o.x = t[c4][r]; o.y = t[c4 + 1][r]; o.z = t[c4 + 2][r]; o.w = t[c4 + 3][r];
    *(ushort4*)&d[(size_t)(n0 + r) * K + k0 + c4] = o;
  }
}

// ---------- five projections (R18 XCD-local map; R19 flag read, no detector) ----------
struct ProjArgs {
  const unsigned short* A[5];
  const void* rawA[5];
  const unsigned short* W[5];
  const unsigned short* bias[5];
  unsigned short* out[5];
  const int* flag;
};

__global__ __launch_bounds__(256) void k_proj(ProjArgs args) {
  const int f32mode = *args.flag;  // broadcast scalar; replaces 900cy detector
  const int id = blockIdx.x;  // 0..767, all live
  int op, by, bx;
  if (id < 256) {
    op = 0; by = id & 31; bx = id >> 5;
  } else {
    int r2 = id - 256;
    op = 1 + (r2 >> 7); r2 &= 127; by = r2 & 15; bx = r2 >> 4;
  }
  const int m0 = by * 64, n0 = bx * 64;
  const unsigned short* A =
      f32mode ? args.A[op] : (const unsigned short*)args.rawA[op];
  const unsigned short* W = args.W[op];
  FRAG_VARS;
  __shared__ __align__(16) unsigned short sm[2][2][64 * 64];  // [buf][A=0/B=1] 32KB
  const int srow = lane >> 3;                       // 0..7 within wave's 8 rows
  const int scol = ((lane & 7) ^ srow) * 8;         // swizzled global elem offset
#pragma unroll
  for (int h = 0; h < 2; ++h) {
    const int row = h * 32 + wv * 8;
    gload16(&A[(size_t)(m0 + row + srow) * 1024 + scol], &sm[0][0][row * 64]);
    gload16(&W[(size_t)(n0 + row + srow) * 1024 + scol], &sm[0][1][row * 64]);
  }
  const int cs0 = ((fq) ^ (fr & 7)) * 8;        // ks=0 slot
  const int cs1 = ((4 + fq) ^ (fr & 7)) * 8;    // ks=1 slot
  for (int kc = 0; kc < 16; ++kc) {
    const int cur = kc & 1;
    __syncthreads();
    if (kc + 1 < 16) {
      const int nxt = cur ^ 1;
      const int k0 = (kc + 1) * 64;
#pragma unroll
      for (int h = 0; h < 2; ++h) {
        const int row = h * 32 + wv * 8;
        gload16(&A[(size_t)(m0 + row + srow) * 1024 + k0 + scol], &sm[nxt][0][row * 64]);
        gload16(&W[(size_t)(n0 + row + srow) * 1024 + k0 + scol], &sm[nxt][1][row * 64]);
      }
    }
    const unsigned short* Ab = sm[cur][0];
    const unsigned short* Bb = sm[cur][1];
    {
      short8_t a0 = *(const short8_t*)&Ab[(mw + fr) * 64 + cs0];
      short8_t a1 = *(const short8_t*)&Ab[(mw + 16 + fr) * 64 + cs0];
      short8_t b0 = *(const short8_t*)&Bb[(nw + fr) * 64 + cs0];
      short8_t b1 = *(const short8_t*)&Bb[(nw + 16 + fr) * 64 + cs0];
      acc00 = MFMA16(a0, b0, acc00);
      acc01 = MFMA16(a0, b1, acc01);
      acc10 = MFMA16(a1, b0, acc10);
      acc11 = MFMA16(a1, b1, acc11);
    }
    {
      short8_t a0 = *(const short8_t*)&Ab[(mw + fr) * 64 + cs1];
      short8_t a1 = *(const short8_t*)&Ab[(mw + 16 + fr) * 64 + cs1];
      short8_t b0 = *(const short8_t*)&Bb[(nw + fr) * 64 + cs1];
      short8_t b1 = *(const short8_t*)&Bb[(nw + 16 + fr) * 64 + cs1];
      acc00 = MFMA16(a0, b0, acc00);
      acc01 = MFMA16(a0, b1, acc01);
      acc10 = MFMA16(a1, b0, acc10);
      acc11 = MFMA16(a1, b1, acc11);
    }
  }
  const float scale = (op == 0) ? 0.044194173824159216f : 1.0f;
  const unsigned short* bias = args.bias[op];
  unsigned short* out = args.out[op];
  GEMM_EPILOGUE({
    const float v = (vv + bf2f(bias[n0 + nl])) * scale;
    const int m = m0 + ml;
    const int n = n0 + nl;
    if (op < 3) {
      out[(size_t)m * 512 + n] = f2bf(v);
    } else {
      const int bb = m >> 6;
      const int ss = m & 63;
      out[(size_t)bb * 32768 + (size_t)n * 64 + ss] = f2bf(v);
    }
  });
}

// ---------- scores: fused exp / row-partials; XCD-local grid + coalesced store ----------
__global__ __launch_bounds__(256) void k_scores(
    const unsigned short* __restrict__ qs, const unsigned short* __restrict__ skey,
    const unsigned short* __restrict__ tkey, unsigned short* __restrict__ scores,
    float* __restrict__ Zp) {
  const int x = blockIdx.x;   // 0..31: b*2 + mhalf
  const int b = x >> 1;
  const int m0 = (x & 1) * 64;
  const int sx = blockIdx.y;  // 0..31: s = sx*2 + {0,1}
  const int tid = threadIdx.x;
  const int lane = tid & 63;
  const int wv = tid >> 6;
  const int mw = (wv >> 1) << 5;
  const int nw = (wv & 1) << 5;
  const int fr = lane & 15;
  const int fq = lane >> 4;
  __shared__ __align__(16) unsigned short qS[2][64 * 64];   // 16KB (epilogue scratch)
  __shared__ __align__(16) unsigned short tkS[2][64 * 64];  // 16KB
  __shared__ __align__(16) unsigned short skL[1024];        // 2KB: 2 s-rows x 512
  f32x4_t acc[2][4];
#pragma unroll
  for (int s = 0; s < 2; ++s)
#pragma unroll
    for (int i = 0; i < 4; ++i) acc[s][i] = (f32x4_t){0.f, 0.f, 0.f, 0.f};
  const unsigned short* qb = qs + ((size_t)b * 128 + m0) * 512;
  const unsigned short* tkb = tkey + (size_t)b * 64 * 512;
  const unsigned short* skb = skey + ((size_t)b * 64 + sx * 2) * 512;
  if (tid < 128) *(uint4*)&skL[tid * 8] = *(const uint4*)&skb[tid * 8];
  const int srow = lane >> 3;
  const int scol = ((lane & 7) ^ srow) * 8;
#pragma unroll
  for (int h = 0; h < 2; ++h) {
    const int row = h * 32 + wv * 8;
    gload16(&qb[(size_t)(row + srow) * 512 + scol], &qS[0][row * 64]);
    gload16(&tkb[(size_t)(row + srow) * 512 + scol], &tkS[0][row * 64]);
  }
  const int cs0 = ((fq) ^ (fr & 7)) * 8;
  const int cs1 = ((4 + fq) ^ (fr & 7)) * 8;
  for (int kc = 0; kc < 8; ++kc) {
    const int cur = kc & 1;
    __syncthreads();  // drains prev prefetch (overlapped with prev compute)
    if (kc + 1 < 8) {
      const int k0 = (kc + 1) * 64;
      const int nxt = cur ^ 1;
#pragma unroll
      for (int h = 0; h < 2; ++h) {
        const int row = h * 32 + wv * 8;
        gload16(&qb[(size_t)(row + srow) * 512 + k0 + scol], &qS[nxt][row * 64]);
        gload16(&tkb[(size_t)(row + srow) * 512 + k0 + scol], &tkS[nxt][row * 64]);
      }
    }
#pragma unroll
    for (int ks = 0; ks < 2; ++ks) {
      const int cs = ks ? cs1 : cs0;
      short8_t a0 = *(const short8_t*)&qS[cur][(mw + fr) * 64 + cs];
      short8_t a1 = *(const short8_t*)&qS[cur][(mw + 16 + fr) * 64 + cs];
      uint4 tq[2];
      tq[0] = *(const uint4*)&tkS[cur][(nw + fr) * 64 + cs];
      tq[1] = *(const uint4*)&tkS[cur][(nw + 16 + fr) * 64 + cs];
      float tlo[2][4], thi[2][4];
#pragma unroll
      for (int h = 0; h < 2; ++h) {
        const unsigned* tw = (const unsigned*)&tq[h];
#pragma unroll
        for (int j = 0; j < 4; ++j) {
          tlo[h][j] = __uint_as_float(tw[j] << 16);
          thi[h][j] = __uint_as_float(tw[j] & 0xffff0000u);
        }
      }
      const int koff = kc * 64 + ks * 32 + fq * 8;  // logical k for sk (broadcast)
#pragma unroll
      for (int s = 0; s < 2; ++s) {
        uint4 skq = *(const uint4*)&skL[s * 512 + koff];
        const unsigned* sw = (const unsigned*)&skq;
        union { short8_t v; unsigned w[4]; } b0, b1;
#pragma unroll
        for (int j = 0; j < 4; ++j) {
          const float slo = __uint_as_float(sw[j] << 16);
          const float shi = __uint_as_float(sw[j] & 0xffff0000u);
          b0.w[j] = __builtin_amdgcn_perm(__float_as_uint(thi[0][j] * shi),
                                          __float_as_uint(tlo[0][j] * slo), 0x07060302);
          b1.w[j] = __builtin_amdgcn_perm(__float_as_uint(thi[1][j] * shi),
                                          __float_as_uint(tlo[1][j] * slo), 0x07060302);
        }
        acc[s][0] = MFMA16(a0, b0.v, acc[s][0]);
        acc[s][1] = MFMA16(a0, b1.v, acc[s][1]);
        acc[s][2] = MFMA16(a1, b0.v, acc[s][2]);
        acc[s][3] = MFMA16(a1, b1.v, acc[s][3]);
      }
    }
  }
  // ---- epilogue: exp -> swizzled LDS stage -> coalesced drain + row sums ----
  __syncthreads();  // all LDS reads of the K-loop done; qS becomes scratch
  unsigned short* es = &qS[0][0];  // [64][128] u16, col XOR-swizzled by row
  float rs0[4] = {0.f, 0.f, 0.f, 0.f};
  float rs1[4] = {0.f, 0.f, 0.f, 0.f};
#pragma unroll
  for (int s = 0; s < 2; ++s)
#pragma unroll
    for (int im = 0; im < 2; ++im)
#pragma unroll
      for (int jn = 0; jn < 2; ++jn) {
        const int cc = s * 64 + nw + jn * 16 + fr;
#pragma unroll
        for (int r = 0; r < 4; ++r) {
          const int row = mw + im * 16 + fq * 4 + r;
          const unsigned short eb = f2bf(__expf(acc[s][im * 2 + jn][r]));
          es[row * 128 + (cc ^ ((row & 7) << 4))] = eb;
          const float e = bf2f(eb);  // sum the SAME rounded value ctx reads
          if (im == 0) rs0[r] += e; else rs1[r] += e;
        }
      }
  // per-row partial sums -> Zp[row][slot], slot = sx*2 + t-half (race-free)
  const int zslot = sx * 2 + (nw >> 5);
#pragma unroll
  for (int im = 0; im < 2; ++im)
#pragma unroll
    for (int r = 0; r < 4; ++r) {
      float p = (im == 0) ? rs0[r] : rs1[r];
      p += __shfl_xor(p, 1);
      p += __shfl_xor(p, 2);
      p += __shfl_xor(p, 4);
      p += __shfl_xor(p, 8);
      if (fr == 0) {
        const int row = m0 + mw + im * 16 + fq * 4 + r;
        Zp[((size_t)b * 128 + row) * 64 + zslot] = p;
      }
    }
  __syncthreads();
  // drain: thread -> (row = tid>>2, 32 u16 at c0=(tid&3)*32), 64B contiguous global
  {
    const int row = tid >> 2;
    const int c0 = (tid & 3) * 32;
    const int sw = (row & 7) << 4;
    unsigned short* dst =
        scores + ((size_t)b * 128 + m0 + row) * 4096 + sx * 128 + c0;
    uint4 v[4];
#pragma unroll
    for (int g = 0; g < 2; ++g) {  // 16-u16 granules stay contiguous under XOR
      const uint4* src = (const uint4*)&es[row * 128 + ((c0 + g * 16) ^ sw)];
      v[g * 2] = src[0];
      v[g * 2 + 1] = src[1];
    }
#pragma unroll
    for (int g = 0; g < 4; ++g) ((uint4*)dst)[g] = v[g];
  }
}

// ---------- ctx: fused s=0..63 + softmax normalization ----------
__global__ __launch_bounds__(512) void k_ctx(
    const unsigned short* __restrict__ p, const unsigned short* __restrict__ svT,
    const unsigned short* __restrict__ tvT, unsigned short* __restrict__ ctx,
    const float* __restrict__ Zp) {
  const int b = blockIdx.x >> 1;
  const int m0 = (blockIdx.x & 1) * 64;
  const int n0 = blockIdx.y * 64;
  const int tid = threadIdx.x;
  const int lane = tid & 63;
  const int wv = tid >> 6;           // 0..7
  const int sgrp = wv >> 2;          // 0/1: which s-half this wave-group does
  const int mw = ((wv >> 1) & 1) << 5;
  const int nw = (wv & 1) << 5;
  const int fr = lane & 15;
  const int fq = lane >> 4;
  f32x4_t acc00 = {0.f, 0.f, 0.f, 0.f};
  f32x4_t acc01 = acc00, acc10 = acc00, acc11 = acc00;
  __shared__ __align__(16) unsigned short smem[2 * 64 * 72];  // 18.4KB
  __shared__ float zrow[64];
  unsigned short* tvl = smem;             // [64][72] t-major value tile
  unsigned short* svl = smem + 64 * 72;   // [64 n][72 pad] s-vector tile
  {
    const unsigned short* tvb = tvT + (size_t)b * 32768 + (size_t)n0 * 64;
    const unsigned short* svb = svT + (size_t)b * 32768 + (size_t)n0 * 64;
    const int r = tid >> 3, c = (tid & 7) * 8;  // 512 threads cover 64x64 once
    *(uint4*)&tvl[r * 72 + c] = *(const uint4*)&tvb[(size_t)r * 64 + c];
    *(uint4*)&svl[r * 72 + c] = *(const uint4*)&svb[(size_t)r * 64 + c];
  }
  if (tid < 64) {  // denominator: sum the 64 per-row partials (L2-hot, 1KB/row)
    const f32x4_t* zp = (const f32x4_t*)(Zp + ((size_t)b * 128 + m0 + tid) * 64);
    f32x4_t s4 = zp[0];
#pragma unroll
    for (int i = 1; i < 16; ++i) {
      const f32x4_t v = zp[i];
      s4[0] += v[0]; s4[1] += v[1]; s4[2] += v[2]; s4[3] += v[3];
    }
    zrow[tid] = s4[0] + s4[1] + s4[2] + s4[3];
  }
  __syncthreads();
  short8_t bv[2][2];
  bv[0][0] = *(const short8_t*)&tvl[(nw + fr) * 72 + fq * 8];
  bv[0][1] = *(const short8_t*)&tvl[(nw + fr) * 72 + 32 + fq * 8];
  bv[1][0] = *(const short8_t*)&tvl[(nw + 16 + fr) * 72 + fq * 8];
  bv[1][1] = *(const short8_t*)&tvl[(nw + 16 + fr) * 72 + 32 + fq * 8];
  const unsigned short* ar0 =
      p + ((size_t)b * 128 + m0 + mw + fr) * 4096 + sgrp * 2048 + fq * 8;
  const unsigned short* ar1 = ar0 + (size_t)16 * 4096;
  uint4 pa[4][2][2];  // 4-deep register prefetch
#pragma unroll
  for (int d = 0; d < 4; ++d) {
    const int off = d * 64;
    pa[d][0][0] = *(const uint4*)(ar0 + off);
    pa[d][0][1] = *(const uint4*)(ar0 + off + 32);
    pa[d][1][0] = *(const uint4*)(ar1 + off);
    pa[d][1][1] = *(const uint4*)(ar1 + off + 32);
  }
#pragma unroll 4
  for (int s = 0; s < 32; ++s) {
    const int sl = s & 3;  // static under unroll-4 (no scratch)
    short8_t a00 = __builtin_bit_cast(short8_t, pa[sl][0][0]);
    short8_t a01 = __builtin_bit_cast(short8_t, pa[sl][0][1]);
    short8_t a10 = __builtin_bit_cast(short8_t, pa[sl][1][0]);
    short8_t a11 = __builtin_bit_cast(short8_t, pa[sl][1][1]);
    if (s + 4 < 32) {
      const int off = (s + 4) * 64;
      pa[sl][0][0] = *(const uint4*)(ar0 + off);
      pa[sl][0][1] = *(const uint4*)(ar0 + off + 32);
      pa[sl][1][0] = *(const uint4*)(ar1 + off);
      pa[sl][1][1] = *(const uint4*)(ar1 + off + 32);
    }
    const f32x4_t z4 = {0.f, 0.f, 0.f, 0.f};
    f32x4_t M00 = MFMA16(a00, bv[0][0], z4);
    M00 = MFMA16(a01, bv[0][1], M00);
    f32x4_t M01 = MFMA16(a00, bv[1][0], z4);
    M01 = MFMA16(a01, bv[1][1], M01);
    f32x4_t M10 = MFMA16(a10, bv[0][0], z4);
    M10 = MFMA16(a11, bv[0][1], M10);
    f32x4_t M11 = MFMA16(a10, bv[1][0], z4);
    M11 = MFMA16(a11, bv[1][1], M11);
    const float sv0 = bf2f(svl[(nw + fr) * 72 + sgrp * 32 + s]);
    const float sv1 = bf2f(svl[(nw + 16 + fr) * 72 + sgrp * 32 + s]);
#pragma unroll
    for (int r = 0; r < 4; ++r) {
      acc00[r] += sv0 * M00[r];
      acc01[r] += sv1 * M01[r];
      acc10[r] += sv0 * M10[r];
      acc11[r] += sv1 * M11[r];
    }
  }
  __syncthreads();  // all waves done reading svl/tvl; reuse smem as f32 scratch
  float* shf = (float*)smem;  // 16KB <= 18.4KB (zrow is separate, preserved)
  const int roff = (wv & 3) * 1024 + lane * 4;
  if (sgrp == 1) {
    *(f32x4_t*)&shf[roff] = acc00;
    *(f32x4_t*)&shf[roff + 256] = acc01;
    *(f32x4_t*)&shf[roff + 512] = acc10;
    *(f32x4_t*)&shf[roff + 768] = acc11;
  }
  __syncthreads();
  if (sgrp == 0) {
    acc00 += *(const f32x4_t*)&shf[roff];
    acc01 += *(const f32x4_t*)&shf[roff + 256];
    acc10 += *(const f32x4_t*)&shf[roff + 512];
    acc11 += *(const f32x4_t*)&shf[roff + 768];
    unsigned short* out = ctx + ((size_t)b * 128 + m0) * 512 + n0;
    GEMM_EPILOGUE({ out[(size_t)ml * 512 + nl] = f2bf(vv / zrow[ml]); });
  }
}

// ---------- out = relu(concat(query, ctx) @ Wo + bo) (R19: flag read) ----------
__global__ __launch_bounds__(256) void k_out(
    const unsigned short* __restrict__ query, const unsigned short* __restrict__ ctx,
    const unsigned short* __restrict__ WoT, const unsigned short* __restrict__ bo,
    void* __restrict__ outv, const void* __restrict__ rawq,
    const int* __restrict__ flag) {
  const int f32mode = *flag;
  const unsigned short* qsrc = f32mode ? query : (const unsigned short*)rawq;
  const int m0 = blockIdx.x * 64, n0 = blockIdx.y * 64;
  FRAG_VARS;
  __shared__ __align__(16) unsigned short sm[2][2][64 * 128];  // [buf][A/B] 64KB
  const int srow4 = lane >> 4;   // 0..3: row within 4-row gload window
  const int c8 = lane & 15;      // 16B-chunk column id
  auto issue = [&](int buf, int kc) {
    const unsigned short* abase;
    size_t astr;
    int kb;
    if (kc < 8) { abase = qsrc + (size_t)m0 * 1024; astr = 1024; kb = kc * 128; }
    else { abase = ctx + (size_t)m0 * 512; astr = 512; kb = (kc - 8) * 128; }
#pragma unroll
    for (int g = 0; g < 4; ++g) {
      const int R0 = wv * 16 + g * 4;
      const int row = R0 + srow4;
      const int col = (c8 ^ ((g * 4 + srow4) & 7)) * 8;
      gload16(&abase[(size_t)row * astr + kb + col], &sm[buf][0][R0 * 128]);
      gload16(&WoT[(size_t)(n0 + row) * 1536 + kc * 128 + col], &sm[buf][1][R0 * 128]);
    }
  };
  issue(0, 0);
  for (int kc = 0; kc < 12; ++kc) {
    const int cur = kc & 1;
    __syncthreads();
    if (kc + 1 < 12) issue(cur ^ 1, kc + 1);
    const unsigned short* Ab = sm[cur][0];
    const unsigned short* Bb = sm[cur][1];
#pragma unroll
    for (int ks = 0; ks < 4; ++ks) {
      const int sl = ((ks * 4 + fq) ^ (fr & 7)) * 8;
      short8_t a0 = *(const short8_t*)&Ab[(mw + fr) * 128 + sl];
      short8_t a1 = *(const short8_t*)&Ab[(mw + 16 + fr) * 128 + sl];
      short8_t b0 = *(const short8_t*)&Bb[(nw + fr) * 128 + sl];
      short8_t b1 = *(const short8_t*)&Bb[(nw + 16 + fr) * 128 + sl];
      acc00 = MFMA16(a0, b0, acc00);
      acc01 = MFMA16(a0, b1, acc01);
      acc10 = MFMA16(a1, b0, acc10);
      acc11 = MFMA16(a1, b1, acc11);
    }
  }
  GEMM_EPILOGUE({
    float v = fmaxf(vv + bf2f(bo[n0 + nl]), 0.f);
    const size_t idx = (size_t)(m0 + ml) * 512 + n0 + nl;
    if (f32mode)
      ((float*)outv)[idx] = v;
    else
      ((unsigned short*)outv)[idx] = f2bf(v);
  });
}

// ---------- launch ----------
extern "C" void kernel_launch(void* const* d_in, const int* in_sizes, int n_in,
                              void* d_out, int out_size, void* d_ws, size_t ws_size,
                              hipStream_t stream) {
  const void* query = d_in[0];
  const void* src = d_in[1];
  const void* trg = d_in[2];
  const void* Wq = d_in[3];
  const void* bq = d_in[4];
  const void* Ws = d_in[5];
  const void* bs = d_in[6];
  const void* Wt = d_in[7];
  const void* bt = d_in[8];
  const void* Wsv = d_in[9];
  const void* bsv = d_in[10];
  const void* Wtv = d_in[11];
  const void* btv = d_in[12];
  const void* Wo = d_in[13];
  const void* bo = d_in[14];

  char* ws = (char*)d_ws;
  size_t off = 0;
  auto alloc = [&](size_t bytes) {
    char* ptr = ws + off;
    off = (off + bytes + 255) & ~(size_t)255;
    return ptr;
  };
  unsigned short* qc = (unsigned short*)alloc((size_t)2048 * 1024 * 2);
  unsigned short* srcc = (unsigned short*)alloc((size_t)1024 * 1024 * 2);
  unsigned short* trgc = (unsigned short*)alloc((size_t)1024 * 1024 * 2);
  unsigned short* biasc = (unsigned short*)alloc((size_t)6 * 512 * 2);
  unsigned short* wT = (unsigned short*)alloc((size_t)5 * 524288 * 2);
  unsigned short* woT = (unsigned short*)alloc((size_t)512 * 1536 * 2);
  unsigned short* q_s = (unsigned short*)alloc((size_t)2048 * 512 * 2);
  unsigned short* s_key = (unsigned short*)alloc((size_t)1024 * 512 * 2);
  unsigned short* t_key = (unsigned short*)alloc((size_t)1024 * 512 * 2);
  unsigned short* sv_T = (unsigned short*)alloc((size_t)16 * 512 * 64 * 2);
  unsigned short* tv_T = (unsigned short*)alloc((size_t)16 * 512 * 64 * 2);
  unsigned short* scores = (unsigned short*)alloc((size_t)2048 * 4096 * 2);
  unsigned short* ctx = (unsigned short*)alloc((size_t)2048 * 512 * 2);
  float* Zp = (float*)alloc((size_t)2048 * 64 * 4);  // [row][64 slots]
  int* flag = (int*)alloc(256);
  (void)ws_size; (void)in_sizes; (void)n_in; (void)out_size;

  PrepArgs pr;
  pr.csrc[0] = query; pr.csrc[1] = src; pr.csrc[2] = trg;
  pr.csrc[3] = bq; pr.csrc[4] = bs; pr.csrc[5] = bt;
  pr.csrc[6] = bsv; pr.csrc[7] = btv; pr.csrc[8] = bo;
  pr.cdst[0] = qc; pr.cdst[1] = srcc; pr.cdst[2] = trgc;
  for (int i = 0; i < 6; ++i) pr.cdst[3 + i] = biasc + i * 512;
  pr.cn[0] = 2048 * 1024; pr.cn[1] = 1024 * 1024; pr.cn[2] = 1024 * 1024;
  for (int i = 0; i < 6; ++i) pr.cn[3 + i] = 512;
  pr.tsrc[0] = Wq; pr.tsrc[1] = Ws; pr.tsrc[2] = Wt;
  pr.tsrc[3] = Wsv; pr.tsrc[4] = Wtv; pr.tsrc[5] = Wo;
  for (int i = 0; i < 5; ++i) { pr.tdst[i] = wT + (size_t)i * 524288; pr.tK[i] = 1024; }
  pr.tdst[5] = woT; pr.tK[5] = 1536;
  pr.flag = flag;
  hipLaunchKernelGGL(k_prep, dim3(16, 48, 15), dim3(256), 0, stream, pr);

  ProjArgs pa;
  pa.A[0] = qc; pa.A[1] = srcc; pa.A[2] = trgc; pa.A[3] = srcc; pa.A[4] = trgc;
  pa.rawA[0] = query; pa.rawA[1] = src; pa.rawA[2] = trg;
  pa.rawA[3] = src; pa.rawA[4] = trg;
  for (int i = 0; i < 5; ++i) pa.W[i] = wT + (size_t)i * 524288;
  for (int i = 0; i < 5; ++i) pa.bias[i] = biasc + i * 512;
  pa.out[0] = q_s; pa.out[1] = s_key; pa.out[2] = t_key; pa.out[3] = sv_T; pa.out[4] = tv_T;
  pa.flag = flag;
  hipLaunchKernelGGL(k_proj, dim3(768), dim3(256), 0, stream, pa);

  hipLaunchKernelGGL(k_scores, dim3(32, 32, 1), dim3(256), 0, stream, q_s, s_key,
                     t_key, scores, Zp);
  hipLaunchKernelGGL(k_ctx, dim3(32, 8), dim3(512), 0, stream, scores, sv_T, tv_T,
                     ctx, Zp);
  hipLaunchKernelGGL(k_out, dim3(32, 8, 1), dim3(256), 0, stream, qc, ctx, woT,
                     biasc + 5 * 512, d_out, query, flag);
}